// Round 10
// baseline (41.804 us; speedup 1.0000x reference)
//
#include <hip/hip_runtime.h>
#include <math.h>

namespace {
constexpr int R_RUNS  = 4096;
constexpr int T_STEPS = 2048;
constexpr int TBW     = 64;              // timesteps per wave (lane = t)
constexpr int RPW     = 32;              // runs per wave
constexpr int NTB     = T_STEPS / TBW;   // 32 t-blocks
constexpr int NRG     = R_RUNS / RPW;    // 128 r-groups
}

__device__ __forceinline__ float sigmoidf_(float x) {
    return 1.0f / (1.0f + expf(-x));
}

// per-lane gh^e, e in [0,63] (branchless binary exponentiation)
__device__ __forceinline__ float powg(float gh, int e) {
    float w = 1.0f, p = gh;
    #pragma unroll
    for (int i = 0; i < 6; ++i) {
        w *= ((e >> i) & 1) ? p : 1.0f;
        p *= p;
    }
    return w;
}

// ---------------------------------------------------------------------------
// Single fused kernel. wave -> (tb = wave&31, rg = wave>>5); lane = t-offset.
// Wave covers t in [64*tb, 64*tb+64) x r in [32*rg, 32*rg+32).
//
// Fast path (wave's 32 G values all equal G[r0]):
//   W_t = sum_{s<t} gh^{t-1-s} z_s  computed per-wave:
//     prefix:  lane L accumulates rows s = L+64m (m<tb) via Horner ratio gh^64,
//              scaled by gh^(63-L); butterfly-reduce -> W_{t0} on all lanes.
//     local:   6-step Hillis-Steele weighted scan (multiplier gh^d) of z rows.
//     W_t = gh^lane * W_{t0} + local.
//   out[r][t] = eta_r.x_t + zeta_r.z_t + gamma_r.W_t   (24 FMA, s_load params)
//   Direct stores: 64 lanes x consecutive t = 256B contiguous per row.
// Fallback (never taken for uniform G): exact serial replay from t=0.
// ---------------------------------------------------------------------------
extern "C" __global__ __launch_bounds__(256, 4)
void dlm_fused(const float* __restrict__ Xt, const float* __restrict__ Zt,
               const float* __restrict__ G, const float* __restrict__ eta,
               const float* __restrict__ zeta, const float* __restrict__ gamma,
               float* __restrict__ out)
{
    const int tid  = threadIdx.x;
    const int wid  = tid >> 6;
    const int lane = tid & 63;
    const int wave = blockIdx.x * 4 + wid;
    const int tb   = wave & (NTB - 1);    // 0..31
    const int rg   = wave >> 5;           // 0..127
    const int t0   = tb * TBW;
    const int r0   = rg * RPW;
    const int t    = t0 + lane;

    // per-lane operand rows (32B/lane, coalesced)
    const float4 xa = *reinterpret_cast<const float4*>(Xt + (size_t)t * 8);
    const float4 xb = *reinterpret_cast<const float4*>(Xt + (size_t)t * 8 + 4);
    const float4 za = *reinterpret_cast<const float4*>(Zt + (size_t)t * 8);
    const float4 zb = *reinterpret_cast<const float4*>(Zt + (size_t)t * 8 + 4);

    const float gw  = G[r0];                       // wave-uniform reference
    const float gv  = G[r0 + (lane & 31)];
    const bool  uni = (__ballot(gv == gw) == ~0ull);

    if (uni) {
        const float gh = sigmoidf_(gw);
        float gh64 = gh;
        #pragma unroll
        for (int i = 0; i < 6; ++i) gh64 *= gh64;

        // ---- W_{t0}: lane L sums rows s = L + 64m, Horner in m (ratio gh^64)
        float acc[8] = {0.f, 0.f, 0.f, 0.f, 0.f, 0.f, 0.f, 0.f};
        for (int m = 0; m < tb; ++m) {             // uniform trip count
            const float* __restrict__ zp = Zt + (size_t)(m * 64 + lane) * 8;
            const float4 pa = *reinterpret_cast<const float4*>(zp);
            const float4 pb = *reinterpret_cast<const float4*>(zp + 4);
            acc[0] = fmaf(gh64, acc[0], pa.x);
            acc[1] = fmaf(gh64, acc[1], pa.y);
            acc[2] = fmaf(gh64, acc[2], pa.z);
            acc[3] = fmaf(gh64, acc[3], pa.w);
            acc[4] = fmaf(gh64, acc[4], pb.x);
            acc[5] = fmaf(gh64, acc[5], pb.y);
            acc[6] = fmaf(gh64, acc[6], pb.z);
            acc[7] = fmaf(gh64, acc[7], pb.w);
        }
        const float wl = powg(gh, 63 - lane);
        #pragma unroll
        for (int i = 0; i < 8; ++i) acc[i] *= wl;
        #pragma unroll
        for (int d = 1; d < 64; d <<= 1) {
            #pragma unroll
            for (int i = 0; i < 8; ++i)
                acc[i] += __shfl_xor(acc[i], d, 64);
        }
        // all lanes now hold W_{t0}[0..7] in acc

        // ---- local weighted inclusive scan: I_j = sum_{m<=j} gh^{j-m} z_{t0+m}
        float I[8] = {za.x, za.y, za.z, za.w, zb.x, zb.y, zb.z, zb.w};
        float p = gh;
        #pragma unroll
        for (int d = 1; d < 64; d <<= 1) {
            #pragma unroll
            for (int i = 0; i < 8; ++i) {
                const float up = __shfl_up(I[i], (unsigned)d, 64);
                if (lane >= d) I[i] = fmaf(p, up, I[i]);
            }
            p *= p;
        }

        // ---- W_t = gh^lane * W_{t0} + I_{lane-1}
        const float wj = powg(gh, lane);
        float Wt[8];
        #pragma unroll
        for (int i = 0; i < 8; ++i) {
            const float L = __shfl_up(I[i], 1u, 64);
            Wt[i] = fmaf(wj, acc[i], (lane == 0) ? 0.0f : L);
        }

        // ---- rank-24 GEMM over 32 runs, direct coalesced stores
        #pragma unroll 4
        for (int rr = 0; rr < RPW; ++rr) {
            const float* __restrict__ e  = eta   + (size_t)(r0 + rr) * 8;  // uniform
            const float* __restrict__ zc = zeta  + (size_t)(r0 + rr) * 8;  // uniform
            const float* __restrict__ gc = gamma + (size_t)(r0 + rr) * 8;  // uniform
            float s = xa.x * e[0];
            s = fmaf(xa.y, e[1], s);
            s = fmaf(xa.z, e[2], s);
            s = fmaf(xa.w, e[3], s);
            s = fmaf(xb.x, e[4], s);
            s = fmaf(xb.y, e[5], s);
            s = fmaf(xb.z, e[6], s);
            s = fmaf(xb.w, e[7], s);
            s = fmaf(za.x, zc[0], s);
            s = fmaf(za.y, zc[1], s);
            s = fmaf(za.z, zc[2], s);
            s = fmaf(za.w, zc[3], s);
            s = fmaf(zb.x, zc[4], s);
            s = fmaf(zb.y, zc[5], s);
            s = fmaf(zb.z, zc[6], s);
            s = fmaf(zb.w, zc[7], s);
            s = fmaf(Wt[0], gc[0], s);
            s = fmaf(Wt[1], gc[1], s);
            s = fmaf(Wt[2], gc[2], s);
            s = fmaf(Wt[3], gc[3], s);
            s = fmaf(Wt[4], gc[4], s);
            s = fmaf(Wt[5], gc[5], s);
            s = fmaf(Wt[6], gc[6], s);
            s = fmaf(Wt[7], gc[7], s);
            out[(size_t)(r0 + rr) * T_STEPS + t] = s;
        }
    } else {
        // ---- exact fallback: serial replay from t=0 (correctness-only path)
        for (int rr = 0; rr < RPW; ++rr) {
            const int r = r0 + rr;
            const float ghr = sigmoidf_(G[r]);
            const float* __restrict__ gc = gamma + (size_t)r * 8;  // uniform
            const float* __restrict__ e  = eta   + (size_t)r * 8;  // uniform
            const float* __restrict__ zc = zeta  + (size_t)r * 8;  // uniform
            float th = 0.0f, mine = 0.0f;
            for (int s2 = 1; s2 <= t0 + 63; ++s2) {
                const float* __restrict__ zr = Zt + (size_t)(s2 - 1) * 8;  // uniform
                float b = zr[0] * gc[0];
                #pragma unroll
                for (int q = 1; q < 8; ++q) b = fmaf(zr[q], gc[q], b);
                th = fmaf(ghr, th, b);
                mine = (s2 == t) ? th : mine;      // theta_t for this lane
            }
            float s = mine;
            s = fmaf(xa.x, e[0], s);  s = fmaf(xa.y, e[1], s);
            s = fmaf(xa.z, e[2], s);  s = fmaf(xa.w, e[3], s);
            s = fmaf(xb.x, e[4], s);  s = fmaf(xb.y, e[5], s);
            s = fmaf(xb.z, e[6], s);  s = fmaf(xb.w, e[7], s);
            s = fmaf(za.x, zc[0], s); s = fmaf(za.y, zc[1], s);
            s = fmaf(za.z, zc[2], s); s = fmaf(za.w, zc[3], s);
            s = fmaf(zb.x, zc[4], s); s = fmaf(zb.y, zc[5], s);
            s = fmaf(zb.z, zc[6], s); s = fmaf(zb.w, zc[7], s);
            out[(size_t)r * T_STEPS + t] = s;
        }
    }
}

// ---------------------------------------------------------------------------
extern "C" void kernel_launch(void* const* d_in, const int* in_sizes, int n_in,
                              void* d_out, int out_size, void* d_ws, size_t ws_size,
                              hipStream_t stream)
{
    const float* Xt    = (const float*)d_in[0];
    const float* Zt    = (const float*)d_in[1];
    const float* G     = (const float*)d_in[2];
    const float* eta   = (const float*)d_in[3];
    const float* zeta  = (const float*)d_in[4];
    const float* gamma = (const float*)d_in[5];
    float* out = (float*)d_out;

    const dim3 blk(256);
    const dim3 grid(NTB * NRG / 4);   // 4096 waves -> 1024 blocks
    dlm_fused<<<grid, blk, 0, stream>>>(Xt, Zt, G, eta, zeta, gamma, out);
}